// Round 2
// baseline (685.942 us; speedup 1.0000x reference)
//
#include <hip/hip_runtime.h>
#include <math.h>

#define B_   8
#define C_   128
#define T_   64
#define N_   256

typedef __attribute__((ext_vector_type(8))) short bf16x8;
typedef __attribute__((ext_vector_type(4))) float f32x4;

// ---------- LDS word offsets (total 17920 floats = 71680 B -> 2 blocks/CU) ----
#define OFF_X   0        // H (staged) -> XC, [64][130] = 8320 words
#define OFF_BH  8320     // in_proj Win-hi chunk, k-major [16][260] = 4160
#define OFF_BL  12480    // in_proj Win-lo chunk = 4160
#define OFF_Z   8320     // after in_proj: Z [64][130] -> overwritten by Y during scan
#define OFF_XD  16640    // x_dbl [64][20] (r0..7 | B0 C0 B1 C1 B2 C2 B3 C3)
#define LDSW    17920
#define OFF_B2H 0        // out_proj Wout-hi chunk [16][132] = 2112 (over dead XC)
#define OFF_B2L 2112

// ---------------- helpers ----------------------------------------------------
__device__ __forceinline__ short f2bf(float f) {            // RNE f32->bf16
  unsigned u = __float_as_uint(f);
  return (short)((u + 0x7FFF + ((u >> 16) & 1)) >> 16);
}
__device__ __forceinline__ float bf2f(short h) {
  return __uint_as_float(((unsigned)(unsigned short)h) << 16);
}
__device__ __forceinline__ void split_pack2(float x, float y, unsigned& wh, unsigned& wl) {
  short hx = f2bf(x), hy = f2bf(y);
  wh = (unsigned)(unsigned short)hx | ((unsigned)(unsigned short)hy << 16);
  short lx = f2bf(x - bf2f(hx)), ly = f2bf(y - bf2f(hy));
  wl = (unsigned)(unsigned short)lx | ((unsigned)(unsigned short)ly << 16);
}
__device__ __forceinline__ void load_split8(const float* p, bf16x8& hi, bf16x8& lo) {
#pragma unroll
  for (int e2 = 0; e2 < 4; ++e2) {
    float2 v = *(const float2*)(p + 2 * e2);
    short hx = f2bf(v.x), hy = f2bf(v.y);
    hi[2 * e2] = hx; hi[2 * e2 + 1] = hy;
    lo[2 * e2] = f2bf(v.x - bf2f(hx));
    lo[2 * e2 + 1] = f2bf(v.y - bf2f(hy));
  }
}
// sum across each quad of lanes via DPP quad_perm (pure VALU, no LDS pipe)
__device__ __forceinline__ float qsum4(float v) {
  int x = __builtin_amdgcn_update_dpp(0, __float_as_int(v), 0xB1, 0xF, 0xF, true);
  v += __int_as_float(x);
  x = __builtin_amdgcn_update_dpp(0, __float_as_int(v), 0x4E, 0xF, 0xF, true);
  v += __int_as_float(x);
  return v;
}

// ---------------- K1: LayerNorm over C + transpose to (B*N, T, C) -----------
__global__ __launch_bounds__(256) void k_ln(const float* __restrict__ x,
                                            const float* __restrict__ gam,
                                            const float* __restrict__ bet,
                                            float* __restrict__ hout) {
  __shared__ float tile[128 * 36];
  __shared__ float ps[8 * 32], pq[8 * 32], mean_s[32], rstd_s[32];
  int bx = blockIdx.x;
  int nt = bx & 7, t = (bx >> 3) & 63, b = bx >> 9;
  int n0 = nt * 32;
  int tid = threadIdx.x;
  const float4* x4 = (const float4*)x;
  for (int it = 0; it < 4; ++it) {
    int idx4 = it * 256 + tid;
    int c = idx4 >> 3, nn4 = idx4 & 7;
    float4 v = x4[((b * C_ + c) * T_ + t) * (N_ / 4) + (n0 >> 2) + nn4];
    *(float4*)&tile[c * 36 + nn4 * 4] = v;
  }
  __syncthreads();
  {
    int nn = tid & 31, cg = tid >> 5;
    float s = 0.f, q = 0.f;
    for (int i = 0; i < 16; ++i) {
      float v = tile[(cg * 16 + i) * 36 + nn];
      s += v; q += v * v;
    }
    ps[cg * 32 + nn] = s; pq[cg * 32 + nn] = q;
  }
  __syncthreads();
  if (tid < 32) {
    float ss = 0.f, qq = 0.f;
    for (int g2 = 0; g2 < 8; ++g2) { ss += ps[g2 * 32 + tid]; qq += pq[g2 * 32 + tid]; }
    float mu = ss * (1.f / 128.f);
    float var = qq * (1.f / 128.f) - mu * mu;
    mean_s[tid] = mu;
    rstd_s[tid] = rsqrtf(var + 1e-5f);
  }
  __syncthreads();
  {
    int c = tid & 127, half = tid >> 7;
    float gm = gam[c], bb = bet[c];
    for (int it = 0; it < 16; ++it) {
      int n = it * 2 + half;
      float v = (tile[c * 36 + n] - mean_s[n]) * rstd_s[n] * gm + bb;
      hout[((b * N_ + n0 + n) * (long)T_ + t) * C_ + c] = v;
    }
  }
}

// ---------------- K2: fused per-sequence Mamba (MFMA split-bf16) ------------
__global__ __launch_bounds__(512, 4) void k_mamba(
    const float* __restrict__ ws_h, float* __restrict__ ws_y,
    const float* __restrict__ Win,   // (256,128)
    const float* __restrict__ convw, // (3,1,128)
    const float* __restrict__ convb, // (128)
    const float* __restrict__ Wx,    // (16,128)
    const float* __restrict__ Wdt,   // (128,8)
    const float* __restrict__ bdt,   // (128)
    const float* __restrict__ Alog,  // (128,4)
    const float* __restrict__ Dp,    // (128)
    const float* __restrict__ Wout)  // (128,128)
{
  extern __shared__ float L[];
  int* Li = (int*)L;
  int bn = blockIdx.x;
  int tid = threadIdx.x;
  int lane = tid & 63;
  int w = tid >> 6;           // wave 0..7
  int r16 = lane & 15, g = lane >> 4;
  const float* hseq = ws_h + (long)bn * (T_ * C_);

  // ---- stage H f32 -> LDS [t][130] (b64 writes, conflict-free) ----
  {
    const float4* h4 = (const float4*)hseq;
    int t = tid & 63, kwg = tid >> 6;
#pragma unroll
    for (int q = 0; q < 4; ++q) {
      float4 v = h4[t * 32 + kwg * 4 + q];
      *(float2*)&L[OFF_X + t * 130 + kwg * 16 + q * 4]     = make_float2(v.x, v.y);
      *(float2*)&L[OFF_X + t * 130 + kwg * 16 + q * 4 + 2] = make_float2(v.z, v.w);
    }
  }

  // ---- in_proj: xz(64x256) = H @ Win^T via split-bf16 MFMA ----
  // wave w owns col-tiles {2w, 2w+1} (j in [32w, 32w+32)), all 4 row-tiles
  f32x4 acc[4][2];
#pragma unroll
  for (int rt = 0; rt < 4; ++rt)
#pragma unroll
    for (int ci = 0; ci < 2; ++ci) acc[rt][ci] = (f32x4){0.f, 0.f, 0.f, 0.f};

  const float4* Win4 = (const float4*)Win;
  union BU { int i[4]; bf16x8 v; };

  for (int kc = 0; kc < 4; ++kc) {
    __syncthreads();   // protect previous chunk reads (and H staging on kc=0)
    // stage Win chunk kc -> Bh/Bl, k-major [16 kw][260]
#pragma unroll
    for (int q = 0; q < 4; ++q) {
      int flat = q * 512 + tid;
      int j = flat >> 3, fq = flat & 7;
      float4 v = Win4[j * 32 + kc * 8 + fq];
      unsigned wh0, wl0, wh1, wl1;
      split_pack2(v.x, v.y, wh0, wl0);
      split_pack2(v.z, v.w, wh1, wl1);
      Li[OFF_BH + (fq * 2 + 0) * 260 + j] = wh0;
      Li[OFF_BH + (fq * 2 + 1) * 260 + j] = wh1;
      Li[OFF_BL + (fq * 2 + 0) * 260 + j] = wl0;
      Li[OFF_BL + (fq * 2 + 1) * 260 + j] = wl1;
    }
    __syncthreads();
    // B fragments for this wave's two col-tiles
    BU bh[2], bl[2];
#pragma unroll
    for (int ci = 0; ci < 2; ++ci) {
      int j = w * 32 + ci * 16 + r16;
#pragma unroll
      for (int q2 = 0; q2 < 4; ++q2) {
        bh[ci].i[q2] = Li[OFF_BH + (g * 4 + q2) * 260 + j];
        bl[ci].i[q2] = Li[OFF_BL + (g * 4 + q2) * 260 + j];
      }
    }
#pragma unroll
    for (int rt = 0; rt < 4; ++rt) {
      bf16x8 ah, al;
      load_split8(&L[OFF_X + (rt * 16 + r16) * 130 + kc * 32 + g * 8], ah, al);
#pragma unroll
      for (int ci = 0; ci < 2; ++ci) {
        acc[rt][ci] = __builtin_amdgcn_mfma_f32_16x16x32_bf16(al, bh[ci].v, acc[rt][ci], 0, 0, 0);
        acc[rt][ci] = __builtin_amdgcn_mfma_f32_16x16x32_bf16(ah, bl[ci].v, acc[rt][ci], 0, 0, 0);
        acc[rt][ci] = __builtin_amdgcn_mfma_f32_16x16x32_bf16(ah, bh[ci].v, acc[rt][ci], 0, 0, 0);
      }
    }
  }
  __syncthreads();
  // scatter xz: waves 0-3 -> XC (over H), waves 4-7 -> Z. C/D: col=l&15, row=4g+r
  {
    int base = (w >= 4) ? OFF_Z : OFF_X;
    int dl0 = (w & 3) * 32;
#pragma unroll
    for (int rt = 0; rt < 4; ++rt)
#pragma unroll
      for (int ci = 0; ci < 2; ++ci)
#pragma unroll
        for (int r = 0; r < 4; ++r)
          L[base + (rt * 16 + g * 4 + r) * 130 + dl0 + ci * 16 + r16] = acc[rt][ci][r];
  }
  __syncthreads();

  // ---- causal depthwise conv(3) + SiLU in place on XC [t][130] ----
  {
    int d = tid & 127, tq = tid >> 7;
    int t0 = tq * 16;
    float w0 = convw[d], w1 = convw[128 + d], w2 = convw[256 + d], cb = convb[d];
    float xin[18];
#pragma unroll
    for (int i = 0; i < 18; ++i) {
      int t = t0 - 2 + i;
      xin[i] = (t < 0) ? 0.f : L[OFF_X + t * 130 + d];
    }
    __syncthreads();
#pragma unroll
    for (int i = 0; i < 16; ++i) {
      float v = fmaf(w2, xin[i + 2], fmaf(w1, xin[i + 1], fmaf(w0, xin[i], cb)));
      L[OFF_X + (t0 + i) * 130 + d] = v / (1.f + expf(-v));
    }
  }
  __syncthreads();

  // ---- x_proj: x_dbl(64x16) = XC^T @ Wx^T (b64 row reads, scalar weights) ----
  {
    int t = tid & 63, rg = tid >> 6;      // rows 2rg, 2rg+1 (wave-uniform rg)
    const float* wx0 = Wx + (2 * rg) * 128;
    const float* wx1 = wx0 + 128;
    float a0 = 0.f, a1 = 0.f;
#pragma unroll 8
    for (int dq = 0; dq < 64; ++dq) {
      float2 xv = *(const float2*)&L[OFF_X + t * 130 + 2 * dq];
      a0 = fmaf(xv.x, wx0[2 * dq], fmaf(xv.y, wx0[2 * dq + 1], a0));
      a1 = fmaf(xv.x, wx1[2 * dq], fmaf(xv.y, wx1[2 * dq + 1], a1));
    }
    int rr0 = 2 * rg, rr1 = 2 * rg + 1;
    int p0 = rr0 < 8 ? rr0 : (rr0 < 12 ? 8 + 2 * (rr0 - 8) : 9 + 2 * (rr0 - 12));
    int p1 = rr1 < 8 ? rr1 : (rr1 < 12 ? 8 + 2 * (rr1 - 8) : 9 + 2 * (rr1 - 12));
    L[OFF_XD + t * 20 + p0] = a0;
    L[OFF_XD + t * 20 + p1] = a1;
  }
  __syncthreads();

  // ---- selective scan: 128 d x 4 states, DPP quad reductions ----
  {
    int d = tid >> 2, s = tid & 3;
    float wA = Wdt[d * 8 + 2 * s], wB = Wdt[d * 8 + 2 * s + 1];
    float bd = bdt[d];
    float As = -expf(Alog[d * 4 + s]);
    float Dd = Dp[d];
    float zreg[16];
#pragma unroll 16
    for (int i = 0; i < 16; ++i) zreg[i] = L[OFF_Z + (4 * i + s) * 130 + d];
    __syncthreads();   // all z preloads done before Y overwrites Z region

    float h = 0.f;
#pragma unroll 16
    for (int tb = 0; tb < 16; ++tb) {
#pragma unroll 4
      for (int si = 0; si < 4; ++si) {
        int t = tb * 4 + si;
        float2 xdp = *(const float2*)&L[OFF_XD + t * 20 + 2 * s];
        float2 bc  = *(const float2*)&L[OFF_XD + t * 20 + 8 + 2 * s];
        float dt = qsum4(fmaf(xdp.x, wA, xdp.y * wB)) + bd;
        dt = (dt > 20.f) ? dt : log1pf(expf(dt));       // softplus
        float xcv = L[OFF_X + t * 130 + d];
        float dA = expf(dt * As);
        float dbx = dt * xcv;
        h = fmaf(h, dA, dbx * bc.x);
        float y = qsum4(h * bc.y);
        if (si == s) {
          y = fmaf(xcv, Dd, y);
          float zv = zreg[tb];
          y *= zv / (1.f + expf(-zv));                  // * silu(z)
          L[OFF_Z + t * 130 + d] = y;                   // Y over Z slot
        }
      }
    }
  }
  __syncthreads();

  // ---- out_proj: out(64x128) = Y @ Wout^T via split-bf16 MFMA ----
  // wave w owns col-tile w (c in [16w,16w+16)), all 4 row-tiles
  f32x4 o[4];
#pragma unroll
  for (int rt = 0; rt < 4; ++rt) o[rt] = (f32x4){0.f, 0.f, 0.f, 0.f};
  const float4* Wout4 = (const float4*)Wout;
  for (int kc = 0; kc < 4; ++kc) {
    __syncthreads();
    // stage Wout chunk kc -> B2h/B2l k-major [16][132] (over dead XC head)
#pragma unroll
    for (int q = 0; q < 2; ++q) {
      int flat = q * 512 + tid;
      int c = flat >> 3, fq = flat & 7;
      float4 v = Wout4[c * 32 + kc * 8 + fq];
      unsigned wh0, wl0, wh1, wl1;
      split_pack2(v.x, v.y, wh0, wl0);
      split_pack2(v.z, v.w, wh1, wl1);
      Li[OFF_B2H + (fq * 2 + 0) * 132 + c] = wh0;
      Li[OFF_B2H + (fq * 2 + 1) * 132 + c] = wh1;
      Li[OFF_B2L + (fq * 2 + 0) * 132 + c] = wl0;
      Li[OFF_B2L + (fq * 2 + 1) * 132 + c] = wl1;
    }
    __syncthreads();
    BU b2h, b2l;
#pragma unroll
    for (int q2 = 0; q2 < 4; ++q2) {
      b2h.i[q2] = Li[OFF_B2H + (g * 4 + q2) * 132 + w * 16 + r16];
      b2l.i[q2] = Li[OFF_B2L + (g * 4 + q2) * 132 + w * 16 + r16];
    }
#pragma unroll
    for (int rt = 0; rt < 4; ++rt) {
      bf16x8 ah, al;
      load_split8(&L[OFF_Z + (rt * 16 + r16) * 130 + kc * 32 + g * 8], ah, al);
      o[rt] = __builtin_amdgcn_mfma_f32_16x16x32_bf16(al, b2h.v, o[rt], 0, 0, 0);
      o[rt] = __builtin_amdgcn_mfma_f32_16x16x32_bf16(ah, b2l.v, o[rt], 0, 0, 0);
      o[rt] = __builtin_amdgcn_mfma_f32_16x16x32_bf16(ah, b2h.v, o[rt], 0, 0, 0);
    }
  }
  // store (bn, t, c)
  {
    float* yout = ws_y + (long)bn * (T_ * C_);
#pragma unroll
    for (int rt = 0; rt < 4; ++rt)
#pragma unroll
      for (int r = 0; r < 4; ++r)
        yout[(rt * 16 + g * 4 + r) * C_ + w * 16 + r16] = o[rt][r];
  }
}

// ---------------- K3: transpose (B*N,T,C) -> (B,C,T,N) ----------------------
__global__ __launch_bounds__(256) void k_out_tr(const float* __restrict__ ws_y,
                                                float* __restrict__ out) {
  __shared__ float tile[32 * 132];
  int bx = blockIdx.x;
  int nt = bx & 7, t = (bx >> 3) & 63, b = bx >> 9;
  int n0 = nt * 32;
  int tid = threadIdx.x;
  const float4* y4 = (const float4*)ws_y;
  for (int it = 0; it < 4; ++it) {
    int idx4 = it * 256 + tid;
    int nn = idx4 >> 5, c4 = idx4 & 31;
    float4 v = y4[((b * N_ + n0 + nn) * (long)T_ + t) * (C_ / 4) + c4];
    *(float4*)&tile[nn * 132 + c4 * 4] = v;
  }
  __syncthreads();
  int nn = tid & 31, cg = tid >> 5;
  for (int i = 0; i < 16; ++i) {
    int c = cg * 16 + i;
    out[((b * C_ + c) * (long)T_ + t) * N_ + n0 + nn] = tile[nn * 132 + c];
  }
}

extern "C" void kernel_launch(void* const* d_in, const int* in_sizes, int n_in,
                              void* d_out, int out_size, void* d_ws, size_t ws_size,
                              hipStream_t stream) {
  const float* x    = (const float*)d_in[0];
  const float* gam  = (const float*)d_in[1];
  const float* bet  = (const float*)d_in[2];
  const float* Win  = (const float*)d_in[3];
  const float* cw   = (const float*)d_in[4];
  const float* cb   = (const float*)d_in[5];
  const float* Wx   = (const float*)d_in[6];
  const float* Wdt  = (const float*)d_in[7];
  const float* bdt  = (const float*)d_in[8];
  const float* Alog = (const float*)d_in[9];
  const float* Dp   = (const float*)d_in[10];
  const float* Wout = (const float*)d_in[11];
  float* out = (float*)d_out;
  float* ws  = (float*)d_ws;   // 64 MB: (B*N, T, C) fp32

  (void)hipFuncSetAttribute((const void*)k_mamba,
                            hipFuncAttributeMaxDynamicSharedMemorySize,
                            LDSW * 4);

  k_ln<<<4096, 256, 0, stream>>>(x, gam, bet, ws);
  k_mamba<<<2048, 512, LDSW * 4, stream>>>(ws, ws, Win, cw, cb, Wx, Wdt,
                                           bdt, Alog, Dp, Wout);
  k_out_tr<<<4096, 256, 0, stream>>>(ws, out);
}

// Round 3
// 645.553 us; speedup vs baseline: 1.0626x; 1.0626x over previous
//
#include <hip/hip_runtime.h>
#include <math.h>

#define B_   8
#define C_   128
#define T_   64
#define N_   256

typedef __attribute__((ext_vector_type(8))) short bf16x8;
typedef __attribute__((ext_vector_type(4))) float f32x4;
typedef unsigned short ushort_t;

#define LOG2E 1.4426950408889634f
#define LN2   0.6931471805599453f

// ---- LDS word layout (18176 words = 72704 B -> 2 blocks/CU) ----
#define R0    0        // H-packed -> XC f32 -> Y-packed (in place), [64][132] = 8448
#define R1    8448     // silu(z) f32, [64][132] = 8448
#define RXD   16896    // x_dbl [64][20]
#define LDSW  18176

#define SELH 0x05040100u
#define SELL 0x07060302u

// ---------------- helpers ----------------------------------------------------
__device__ __forceinline__ unsigned bfhi(float x) {  // RNE f32->bf16 (as u16)
  unsigned u = __float_as_uint(x);
  return (u + 0x7FFF + ((u >> 16) & 1)) >> 16;
}
__device__ __forceinline__ unsigned packsplit(float x) {  // (lo<<16)|hi
  unsigned hi = bfhi(x);
  float rem = x - __uint_as_float(hi << 16);
  unsigned lo = bfhi(rem);
  return (hi & 0xFFFFu) | (lo << 16);
}
__device__ __forceinline__ float fsilu(float v) {
  return v * __builtin_amdgcn_rcpf(1.0f + __builtin_amdgcn_exp2f(-LOG2E * v));
}
// sum across each quad of lanes via DPP quad_perm (pure VALU)
__device__ __forceinline__ float qsum4(float v) {
  int x = __builtin_amdgcn_update_dpp(0, __float_as_int(v), 0xB1, 0xF, 0xF, true);
  v += __int_as_float(x);
  x = __builtin_amdgcn_update_dpp(0, __float_as_int(v), 0x4E, 0xF, 0xF, true);
  v += __int_as_float(x);
  return v;
}
union BU { uint4 q; bf16x8 v; unsigned u[4]; };

// ---------------- K0: pre-split weights into MFMA fragment layout -----------
// chunk index = (row*4+kc)*8 + g*2 + p ; each chunk = 8 bf16 (16B) = k range
// [kc*32+g*8, +8) of row, plane p (0=hi,1=lo).
__global__ __launch_bounds__(512) void k_wsplit(const float* __restrict__ Win,
                                                const float* __restrict__ Wout,
                                                ushort_t* __restrict__ wsi,
                                                ushort_t* __restrict__ wso) {
  int idx = blockIdx.x * 512 + threadIdx.x;
  const float* src;
  ushort_t* dst;
  if (idx < 1024) {
    int row = idx >> 2, kc = idx & 3;
    src = Win + row * 128 + kc * 32;
    dst = wsi + (row * 4 + kc) * 64;
  } else if (idx < 1536) {
    int k = idx - 1024;
    int row = k >> 2, kc = k & 3;
    src = Wout + row * 128 + kc * 32;
    dst = wso + (row * 4 + kc) * 64;
  } else {
    return;
  }
  for (int g = 0; g < 4; ++g) {
    unsigned hw[4], lw[4];
#pragma unroll
    for (int e2 = 0; e2 < 4; ++e2) {
      float x0 = src[g * 8 + 2 * e2], x1 = src[g * 8 + 2 * e2 + 1];
      unsigned p0 = packsplit(x0), p1 = packsplit(x1);
      hw[e2] = (p0 & 0xFFFFu) | (p1 << 16);
      lw[e2] = (p0 >> 16) | (p1 & 0xFFFF0000u);
    }
    *(uint4*)(dst + (g * 2 + 0) * 8) = make_uint4(hw[0], hw[1], hw[2], hw[3]);
    *(uint4*)(dst + (g * 2 + 1) * 8) = make_uint4(lw[0], lw[1], lw[2], lw[3]);
  }
}

// ---------------- K1: LayerNorm over C + transpose to (B*N, T, C) -----------
__global__ __launch_bounds__(256) void k_ln(const float* __restrict__ x,
                                            const float* __restrict__ gam,
                                            const float* __restrict__ bet,
                                            float* __restrict__ hout) {
  __shared__ float tile[128 * 36];
  __shared__ float ps[8 * 32], pq[8 * 32], mean_s[32], rstd_s[32];
  int bx = blockIdx.x;
  int nt = bx & 7, t = (bx >> 3) & 63, b = bx >> 9;
  int n0 = nt * 32;
  int tid = threadIdx.x;
  const float4* x4 = (const float4*)x;
  for (int it = 0; it < 4; ++it) {
    int idx4 = it * 256 + tid;
    int c = idx4 >> 3, nn4 = idx4 & 7;
    float4 v = x4[((b * C_ + c) * T_ + t) * (N_ / 4) + (n0 >> 2) + nn4];
    *(float4*)&tile[c * 36 + nn4 * 4] = v;
  }
  __syncthreads();
  {
    int nn = tid & 31, cg = tid >> 5;
    float s = 0.f, q = 0.f;
    for (int i = 0; i < 16; ++i) {
      float v = tile[(cg * 16 + i) * 36 + nn];
      s += v; q += v * v;
    }
    ps[cg * 32 + nn] = s; pq[cg * 32 + nn] = q;
  }
  __syncthreads();
  if (tid < 32) {
    float ss = 0.f, qq = 0.f;
    for (int g2 = 0; g2 < 8; ++g2) { ss += ps[g2 * 32 + tid]; qq += pq[g2 * 32 + tid]; }
    float mu = ss * (1.f / 128.f);
    float var = qq * (1.f / 128.f) - mu * mu;
    mean_s[tid] = mu;
    rstd_s[tid] = rsqrtf(var + 1e-5f);
  }
  __syncthreads();
  {
    int c = tid & 127, half = tid >> 7;
    float gm = gam[c], bb = bet[c];
    for (int it = 0; it < 16; ++it) {
      int n = it * 2 + half;
      float v = (tile[c * 36 + n] - mean_s[n]) * rstd_s[n] * gm + bb;
      hout[((b * N_ + n0 + n) * (long)T_ + t) * C_ + c] = v;
    }
  }
}

// ---------------- K2: fused per-sequence Mamba -------------------------------
__global__ __launch_bounds__(512, 4) void k_mamba(
    const float* ws_h, float* ws_y,
    const ushort_t* __restrict__ wsi,   // pre-split Win fragments
    const ushort_t* __restrict__ wso,   // pre-split Wout fragments
    const float* __restrict__ convw,    // (3,1,128)
    const float* __restrict__ convb,    // (128)
    const float* __restrict__ Wx,       // (16,128)
    const float* __restrict__ Wdt,      // (128,8)
    const float* __restrict__ bdt,      // (128)
    const float* __restrict__ Alog,     // (128,4)
    const float* __restrict__ Dp)       // (128)
{
  extern __shared__ float L[];
  unsigned* Li = (unsigned*)L;
  int bn = blockIdx.x;
  int tid = threadIdx.x;
  int lane = tid & 63;
  int w = tid >> 6;                 // wave 0..7
  int r16 = lane & 15, g = lane >> 4;
  const float* hseq = ws_h + (long)bn * (T_ * C_);
  const uint4* wsi4 = (const uint4*)wsi;
  const uint4* wso4 = (const uint4*)wso;

  // ---- Phase 0: stage H as packed split-bf16 words [t][132] ----
  {
    const float4* h4 = (const float4*)hseq;
    int ts = tid >> 3, kg = tid & 7;
#pragma unroll
    for (int q = 0; q < 4; ++q) {
      float4 v = h4[ts * 32 + kg * 4 + q];
      uint4 pw = make_uint4(packsplit(v.x), packsplit(v.y), packsplit(v.z), packsplit(v.w));
      *(uint4*)&Li[R0 + ts * 132 + kg * 16 + q * 4] = pw;
    }
  }
  __syncthreads();

  // ---- Phase 1: in_proj xz(64x256) = H @ Win^T (split-bf16 MFMA) ----
  f32x4 acc[4][2];
#pragma unroll
  for (int rt = 0; rt < 4; ++rt)
#pragma unroll
    for (int ci = 0; ci < 2; ++ci) acc[rt][ci] = (f32x4){0.f, 0.f, 0.f, 0.f};

#pragma unroll
  for (int kc = 0; kc < 4; ++kc) {
    BU bh[2], bl[2];
#pragma unroll
    for (int ci = 0; ci < 2; ++ci) {
      int j = w * 32 + ci * 16 + r16;
      int cb = (j * 4 + kc) * 8 + g * 2;
      bh[ci].q = wsi4[cb];
      bl[ci].q = wsi4[cb + 1];
    }
#pragma unroll
    for (int rt = 0; rt < 4; ++rt) {
      int idx = (rt * 16 + r16) * 132 + kc * 32 + g * 8;
      uint4 wa = *(const uint4*)&Li[R0 + idx];
      uint4 wb = *(const uint4*)&Li[R0 + idx + 4];
      BU ah, al;
      ah.u[0] = __builtin_amdgcn_perm(wa.y, wa.x, SELH);
      ah.u[1] = __builtin_amdgcn_perm(wa.w, wa.z, SELH);
      ah.u[2] = __builtin_amdgcn_perm(wb.y, wb.x, SELH);
      ah.u[3] = __builtin_amdgcn_perm(wb.w, wb.z, SELH);
      al.u[0] = __builtin_amdgcn_perm(wa.y, wa.x, SELL);
      al.u[1] = __builtin_amdgcn_perm(wa.w, wa.z, SELL);
      al.u[2] = __builtin_amdgcn_perm(wb.y, wb.x, SELL);
      al.u[3] = __builtin_amdgcn_perm(wb.w, wb.z, SELL);
#pragma unroll
      for (int ci = 0; ci < 2; ++ci) {
        acc[rt][ci] = __builtin_amdgcn_mfma_f32_16x16x32_bf16(al.v, bh[ci].v, acc[rt][ci], 0, 0, 0);
        acc[rt][ci] = __builtin_amdgcn_mfma_f32_16x16x32_bf16(ah.v, bl[ci].v, acc[rt][ci], 0, 0, 0);
        acc[rt][ci] = __builtin_amdgcn_mfma_f32_16x16x32_bf16(ah.v, bh[ci].v, acc[rt][ci], 0, 0, 0);
      }
    }
  }
  __syncthreads();   // all H reads done before XC overwrites R0

  // ---- Phase 2: scatter xz; waves 0-3 -> XC f32 (R0), waves 4-7 -> silu(z) (R1)
  {
    int dl0 = (w & 3) * 32;
    if (w < 4) {
#pragma unroll
      for (int rt = 0; rt < 4; ++rt)
#pragma unroll
        for (int ci = 0; ci < 2; ++ci)
#pragma unroll
          for (int r = 0; r < 4; ++r)
            L[R0 + (rt * 16 + g * 4 + r) * 132 + dl0 + ci * 16 + r16] = acc[rt][ci][r];
    } else {
#pragma unroll
      for (int rt = 0; rt < 4; ++rt)
#pragma unroll
        for (int ci = 0; ci < 2; ++ci)
#pragma unroll
          for (int r = 0; r < 4; ++r)
            L[R1 + (rt * 16 + g * 4 + r) * 132 + dl0 + ci * 16 + r16] = fsilu(acc[rt][ci][r]);
    }
  }
  __syncthreads();

  // ---- Phase 3: causal depthwise conv(3) + SiLU in place on XC ----
  {
    int d = tid & 127, tq = tid >> 7;
    int t0 = tq * 16;
    float w0 = convw[d], w1 = convw[128 + d], w2 = convw[256 + d], cb = convb[d];
    float xin[18];
#pragma unroll
    for (int i = 0; i < 18; ++i) {
      int t = t0 - 2 + i;
      xin[i] = (t < 0) ? 0.f : L[R0 + t * 132 + d];
    }
    __syncthreads();
#pragma unroll
    for (int i = 0; i < 16; ++i) {
      float v = fmaf(w2, xin[i + 2], fmaf(w1, xin[i + 1], fmaf(w0, xin[i], cb)));
      L[R0 + (t0 + i) * 132 + d] = fsilu(v);
    }
  }
  __syncthreads();

  // ---- Phase 4: x_proj x_dbl(64x16) = XC @ Wx^T ----
  {
    int t = tid & 63, rg = tid >> 6;
    int rr0 = 2 * rg, rr1 = 2 * rg + 1;
    const float4* wx4 = (const float4*)Wx;
    float a0 = 0.f, a1 = 0.f;
#pragma unroll
    for (int q = 0; q < 32; ++q) {
      float4 xv = *(const float4*)&L[R0 + t * 132 + q * 4];
      float4 w0 = wx4[rr0 * 32 + q];
      float4 w1 = wx4[rr1 * 32 + q];
      a0 = fmaf(xv.x, w0.x, fmaf(xv.y, w0.y, fmaf(xv.z, w0.z, fmaf(xv.w, w0.w, a0))));
      a1 = fmaf(xv.x, w1.x, fmaf(xv.y, w1.y, fmaf(xv.z, w1.z, fmaf(xv.w, w1.w, a1))));
    }
    int p0 = rr0 < 8 ? rr0 : (rr0 < 12 ? 8 + 2 * (rr0 - 8) : 9 + 2 * (rr0 - 12));
    int p1 = rr1 < 8 ? rr1 : (rr1 < 12 ? 8 + 2 * (rr1 - 8) : 9 + 2 * (rr1 - 12));
    L[RXD + t * 20 + p0] = a0;
    L[RXD + t * 20 + p1] = a1;
  }
  __syncthreads();

  // ---- Phase 5: selective scan, 128 d x 4 s; Y packed in place over XC ----
  {
    int d = tid >> 2, s = tid & 3;
    float wA = Wdt[d * 8 + 2 * s], wB = Wdt[d * 8 + 2 * s + 1];
    float bd = bdt[d];
    float As2 = -expf(Alog[d * 4 + s]) * LOG2E;
    float Dd = Dp[d];
    float h = 0.f;
#pragma unroll 4
    for (int t = 0; t < 64; ++t) {
      float2 xdp = *(const float2*)&L[RXD + t * 20 + 2 * s];
      float2 bc  = *(const float2*)&L[RXD + t * 20 + 8 + 2 * s];
      float dtv = qsum4(fmaf(xdp.x, wA, xdp.y * wB)) + bd;
      float e = __builtin_amdgcn_exp2f(dtv * LOG2E);
      float sp = LN2 * __builtin_amdgcn_logf(1.0f + e);
      dtv = (dtv > 20.f) ? dtv : sp;                 // softplus
      float xcv = L[R0 + t * 132 + d];
      float dA = __builtin_amdgcn_exp2f(dtv * As2);
      float dbx = dtv * xcv;
      h = fmaf(h, dA, dbx * bc.x);
      float y = qsum4(h * bc.y);                     // full sum in all 4 lanes
      y = fmaf(xcv, Dd, y);
      y *= L[R1 + t * 132 + d];                      // * silu(z) (precomputed)
      unsigned yw = packsplit(y);
      if ((t & 3) == s) Li[R0 + t * 132 + d] = yw;   // Y over dead XC cell
    }
  }
  __syncthreads();

  // ---- Phase 6: out_proj out(64x128) = Y @ Wout^T (split-bf16 MFMA) ----
  {
    f32x4 o[4];
#pragma unroll
    for (int rt = 0; rt < 4; ++rt) o[rt] = (f32x4){0.f, 0.f, 0.f, 0.f};
#pragma unroll
    for (int kc = 0; kc < 4; ++kc) {
      int c = w * 16 + r16;
      int cb = (c * 4 + kc) * 8 + g * 2;
      BU b2h, b2l;
      b2h.q = wso4[cb];
      b2l.q = wso4[cb + 1];
#pragma unroll
      for (int rt = 0; rt < 4; ++rt) {
        int idx = (rt * 16 + r16) * 132 + kc * 32 + g * 8;
        uint4 wa = *(const uint4*)&Li[R0 + idx];
        uint4 wb = *(const uint4*)&Li[R0 + idx + 4];
        BU ah, al;
        ah.u[0] = __builtin_amdgcn_perm(wa.y, wa.x, SELH);
        ah.u[1] = __builtin_amdgcn_perm(wa.w, wa.z, SELH);
        ah.u[2] = __builtin_amdgcn_perm(wb.y, wb.x, SELH);
        ah.u[3] = __builtin_amdgcn_perm(wb.w, wb.z, SELH);
        al.u[0] = __builtin_amdgcn_perm(wa.y, wa.x, SELL);
        al.u[1] = __builtin_amdgcn_perm(wa.w, wa.z, SELL);
        al.u[2] = __builtin_amdgcn_perm(wb.y, wb.x, SELL);
        al.u[3] = __builtin_amdgcn_perm(wb.w, wb.z, SELL);
        o[rt] = __builtin_amdgcn_mfma_f32_16x16x32_bf16(al.v, b2h.v, o[rt], 0, 0, 0);
        o[rt] = __builtin_amdgcn_mfma_f32_16x16x32_bf16(ah.v, b2l.v, o[rt], 0, 0, 0);
        o[rt] = __builtin_amdgcn_mfma_f32_16x16x32_bf16(ah.v, b2h.v, o[rt], 0, 0, 0);
      }
    }
    float* yout = ws_y + (long)bn * (T_ * C_);
#pragma unroll
    for (int rt = 0; rt < 4; ++rt)
#pragma unroll
      for (int r = 0; r < 4; ++r)
        yout[(rt * 16 + g * 4 + r) * C_ + w * 16 + r16] = o[rt][r];
  }
}

// ---------------- K3: transpose (B*N,T,C) -> (B,C,T,N) ----------------------
__global__ __launch_bounds__(256) void k_out_tr(const float* __restrict__ ws_y,
                                                float* __restrict__ out) {
  __shared__ float tile[32 * 132];
  int bx = blockIdx.x;
  int nt = bx & 7, t = (bx >> 3) & 63, b = bx >> 9;
  int n0 = nt * 32;
  int tid = threadIdx.x;
  const float4* y4 = (const float4*)ws_y;
  for (int it = 0; it < 4; ++it) {
    int idx4 = it * 256 + tid;
    int nn = idx4 >> 5, c4 = idx4 & 31;
    float4 v = y4[((b * N_ + n0 + nn) * (long)T_ + t) * (C_ / 4) + c4];
    *(float4*)&tile[nn * 132 + c4 * 4] = v;
  }
  __syncthreads();
  int nn = tid & 31, cg = tid >> 5;
  for (int i = 0; i < 16; ++i) {
    int c = cg * 16 + i;
    out[((b * C_ + c) * (long)T_ + t) * N_ + n0 + nn] = tile[nn * 132 + c];
  }
}

extern "C" void kernel_launch(void* const* d_in, const int* in_sizes, int n_in,
                              void* d_out, int out_size, void* d_ws, size_t ws_size,
                              hipStream_t stream) {
  const float* x    = (const float*)d_in[0];
  const float* gam  = (const float*)d_in[1];
  const float* bet  = (const float*)d_in[2];
  const float* Win  = (const float*)d_in[3];
  const float* cw   = (const float*)d_in[4];
  const float* cb   = (const float*)d_in[5];
  const float* Wx   = (const float*)d_in[6];
  const float* Wdt  = (const float*)d_in[7];
  const float* bdt  = (const float*)d_in[8];
  const float* Alog = (const float*)d_in[9];
  const float* Dp   = (const float*)d_in[10];
  const float* Wout = (const float*)d_in[11];
  float* out = (float*)d_out;
  float* ws  = (float*)d_ws;   // 64 MiB: (B*N, T, C) fp32, in-place H -> y

  // split-weight storage: ws tail if it fits, else scribble d_out
  // (K3 fully overwrites d_out afterwards; stream order makes this safe)
  const size_t HBYTES = 67108864ull;           // 64 MiB
  const size_t WBYTES = 131072ull + 65536ull;  // Win-split + Wout-split
  char* wtail;
  if (ws_size >= HBYTES + WBYTES) wtail = (char*)d_ws + HBYTES;
  else                            wtail = (char*)d_out;
  ushort_t* wsi = (ushort_t*)wtail;
  ushort_t* wso = (ushort_t*)(wtail + 131072);

  (void)hipFuncSetAttribute((const void*)k_mamba,
                            hipFuncAttributeMaxDynamicSharedMemorySize,
                            LDSW * 4);

  k_wsplit<<<3, 512, 0, stream>>>(Win, Wout, wsi, wso);
  k_ln<<<4096, 256, 0, stream>>>(x, gam, bet, ws);
  k_mamba<<<2048, 512, LDSW * 4, stream>>>(ws, ws, wsi, wso, cw, cb, Wx, Wdt,
                                           bdt, Alog, Dp);
  k_out_tr<<<4096, 256, 0, stream>>>(ws, out);
}

// Round 4
// 218.538 us; speedup vs baseline: 3.1388x; 2.9540x over previous
//
#include <hip/hip_runtime.h>
#include <math.h>

#define B_   8
#define C_   128
#define T_   64
#define N_   256
#define NSEQ 8

typedef __attribute__((ext_vector_type(8))) short bf16x8;
typedef __attribute__((ext_vector_type(4))) float f32x4;
typedef unsigned short ushort_t;

#define LOG2E 1.4426950408889634f
#define LN2   0.6931471805599453f

// ---- LDS word layout (27136 words = 108544 B -> 1 block/CU) ----
#define R0   0       // [64][132]: packed H -> f32 xz(x) -> packed XC -> packed Y
#define R1   8448    // [128][68]: silu(z) f32, [d][t]
#define RXD  17152   // [64][20]: x_dbl interleaved: slot s*4 = {xd2s, xd2s+1, Bs, Cs}
#define RXT  18432   // [128][68]: silu(conv(x)) f32, [d][t]
#define LDSW 27136

#define SELH 0x05040100u
#define SELL 0x07060302u

// ---------------- helpers ----------------------------------------------------
__device__ __forceinline__ unsigned bfhi(float x) {  // RNE f32->bf16 (as u16)
  unsigned u = __float_as_uint(x);
  return (u + 0x7FFF + ((u >> 16) & 1)) >> 16;
}
__device__ __forceinline__ unsigned packsplit(float x) {  // (lo<<16)|hi
  unsigned hi = bfhi(x);
  float rem = x - __uint_as_float(hi << 16);
  unsigned lo = bfhi(rem);
  return (hi & 0xFFFFu) | (lo << 16);
}
__device__ __forceinline__ float fsilu(float v) {
  return v * __builtin_amdgcn_rcpf(1.0f + __builtin_amdgcn_exp2f(-LOG2E * v));
}
__device__ __forceinline__ float qsum4(float v) {  // sum over lane quads (DPP)
  int x = __builtin_amdgcn_update_dpp(0, __float_as_int(v), 0xB1, 0xF, 0xF, true);
  v += __int_as_float(x);
  x = __builtin_amdgcn_update_dpp(0, __float_as_int(v), 0x4E, 0xF, 0xF, true);
  v += __int_as_float(x);
  return v;
}
union BU { uint4 q; bf16x8 v; unsigned u[4]; };

// ---------------- K0: pre-split weights into MFMA fragment layout -----------
// chunk = (row*4+kc)*8 + g*2 + p ; 8 bf16 (16B) covering k in [kc*32+g*8, +8)
__global__ __launch_bounds__(512) void k_wsplit(const float* __restrict__ Win,
                                                const float* __restrict__ Wout,
                                                const float* __restrict__ Wx,
                                                ushort_t* __restrict__ wsi,
                                                ushort_t* __restrict__ wso,
                                                ushort_t* __restrict__ wsx) {
  int idx = blockIdx.x * 512 + threadIdx.x;
  const float* src;
  ushort_t* dst;
  if (idx < 1024) {
    int row = idx >> 2, kc = idx & 3;
    src = Win + row * 128 + kc * 32;
    dst = wsi + (row * 4 + kc) * 64;
  } else if (idx < 1536) {
    int k = idx - 1024;
    int row = k >> 2, kc = k & 3;
    src = Wout + row * 128 + kc * 32;
    dst = wso + (row * 4 + kc) * 64;
  } else if (idx < 1600) {
    int k = idx - 1536;
    int row = k >> 2, kc = k & 3;
    src = Wx + row * 128 + kc * 32;
    dst = wsx + (row * 4 + kc) * 64;
  } else {
    return;
  }
  for (int g = 0; g < 4; ++g) {
    unsigned hw[4], lw[4];
#pragma unroll
    for (int e2 = 0; e2 < 4; ++e2) {
      float x0 = src[g * 8 + 2 * e2], x1 = src[g * 8 + 2 * e2 + 1];
      unsigned p0 = packsplit(x0), p1 = packsplit(x1);
      hw[e2] = (p0 & 0xFFFFu) | (p1 << 16);
      lw[e2] = (p0 >> 16) | (p1 & 0xFFFF0000u);
    }
    *(uint4*)(dst + (g * 2 + 0) * 8) = make_uint4(hw[0], hw[1], hw[2], hw[3]);
    *(uint4*)(dst + (g * 2 + 1) * 8) = make_uint4(lw[0], lw[1], lw[2], lw[3]);
  }
}

// ---------------- K1: LayerNorm over C + transpose to (B*N, T, C) -----------
__global__ __launch_bounds__(256) void k_ln(const float* __restrict__ x,
                                            const float* __restrict__ gam,
                                            const float* __restrict__ bet,
                                            float* __restrict__ hout) {
  __shared__ float tile[128 * 36];
  __shared__ float ps[8 * 32], pq[8 * 32], mean_s[32], rstd_s[32];
  int bx = blockIdx.x;
  int nt = bx & 7, t = (bx >> 3) & 63, b = bx >> 9;
  int n0 = nt * 32;
  int tid = threadIdx.x;
  const float4* x4 = (const float4*)x;
  for (int it = 0; it < 4; ++it) {
    int idx4 = it * 256 + tid;
    int c = idx4 >> 3, nn4 = idx4 & 7;
    float4 v = x4[((b * C_ + c) * T_ + t) * (N_ / 4) + (n0 >> 2) + nn4];
    *(float4*)&tile[c * 36 + nn4 * 4] = v;
  }
  __syncthreads();
  {
    int nn = tid & 31, cg = tid >> 5;
    float s = 0.f, q = 0.f;
    for (int i = 0; i < 16; ++i) {
      float v = tile[(cg * 16 + i) * 36 + nn];
      s += v; q += v * v;
    }
    ps[cg * 32 + nn] = s; pq[cg * 32 + nn] = q;
  }
  __syncthreads();
  if (tid < 32) {
    float ss = 0.f, qq = 0.f;
    for (int g2 = 0; g2 < 8; ++g2) { ss += ps[g2 * 32 + tid]; qq += pq[g2 * 32 + tid]; }
    float mu = ss * (1.f / 128.f);
    float var = qq * (1.f / 128.f) - mu * mu;
    mean_s[tid] = mu;
    rstd_s[tid] = rsqrtf(var + 1e-5f);
  }
  __syncthreads();
  {
    int c = tid & 127, half = tid >> 7;
    float gm = gam[c], bb = bet[c];
    for (int it = 0; it < 16; ++it) {
      int n = it * 2 + half;
      float v = (tile[c * 36 + n] - mean_s[n]) * rstd_s[n] * gm + bb;
      hout[((b * N_ + n0 + n) * (long)T_ + t) * C_ + c] = v;
    }
  }
}

// ---------------- K2: fused Mamba, NSEQ sequences/block, reg weights --------
__global__ __launch_bounds__(512, 2) void k_mamba(
    float* ws,                          // (B*N, T, C) in-place H -> y
    const ushort_t* __restrict__ wsi,   // pre-split Win fragments
    const ushort_t* __restrict__ wso,   // pre-split Wout fragments
    const ushort_t* __restrict__ wsx,   // pre-split Wx fragments
    const float* __restrict__ convw,    // (3,1,128)
    const float* __restrict__ convb,    // (128)
    const float* __restrict__ Wdt,      // (128,8)
    const float* __restrict__ bdt,      // (128)
    const float* __restrict__ Alog,     // (128,4)
    const float* __restrict__ Dp)       // (128)
{
  extern __shared__ float L[];
  unsigned* Li = (unsigned*)L;
  int tid = threadIdx.x;
  int lane = tid & 63;
  int w = tid >> 6;                 // wave 0..7
  int r16 = lane & 15, g = lane >> 4;
  const uint4* wsi4 = (const uint4*)wsi;
  const uint4* wso4 = (const uint4*)wso;
  const uint4* wsx4 = (const uint4*)wsx;

  // ---- persistent weight fragments (VGPR-resident across NSEQ) ----
  uint4 wih[2][4], wil[2][4], woh[4], wol[4];
#pragma unroll
  for (int ci = 0; ci < 2; ++ci)
#pragma unroll
    for (int kc = 0; kc < 4; ++kc) {
      int cb = ((w * 32 + ci * 16 + r16) * 4 + kc) * 8 + g * 2;
      wih[ci][kc] = wsi4[cb];
      wil[ci][kc] = wsi4[cb + 1];
    }
#pragma unroll
  for (int kc = 0; kc < 4; ++kc) {
    int cb = ((w * 16 + r16) * 4 + kc) * 8 + g * 2;
    woh[kc] = wso4[cb];
    wol[kc] = wso4[cb + 1];
  }
  // ---- per-thread constants (fixed role across sequences) ----
  int dc = tid & 127, tq = tid >> 7;                  // conv role
  float cw0 = convw[dc], cw1 = convw[128 + dc], cw2 = convw[256 + dc];
  float cbv = convb[dc];
  int ds = tid >> 2, ss = tid & 3;                    // scan role
  float wA = Wdt[ds * 8 + 2 * ss], wB = Wdt[ds * 8 + 2 * ss + 1];
  float bd = bdt[ds];
  float As2 = -expf(Alog[ds * 4 + ss]) * LOG2E;
  float Dd = Dp[ds];

  for (int iseq = 0; iseq < NSEQ; ++iseq) {
    float* hseq = ws + ((long)blockIdx.x * NSEQ + iseq) * (T_ * C_);

    // ---- P0: stage H as packed split-bf16, row-swizzled ----
    {
      const float4* h4 = (const float4*)hseq;
      int ts = tid >> 3, kg = tid & 7;
      int sw = (ts & 7) << 2;
#pragma unroll
      for (int q = 0; q < 4; ++q) {
        float4 v = h4[ts * 32 + kg * 4 + q];
        uint4 pw = make_uint4(packsplit(v.x), packsplit(v.y), packsplit(v.z), packsplit(v.w));
        *(uint4*)&Li[R0 + ts * 132 + ((kg * 16 + q * 4) ^ sw)] = pw;
      }
    }
    __syncthreads();

    // ---- P1: in_proj xz(64x256) = H @ Win^T ----
    f32x4 acc[4][2];
#pragma unroll
    for (int rt = 0; rt < 4; ++rt)
#pragma unroll
      for (int ci = 0; ci < 2; ++ci) acc[rt][ci] = (f32x4){0.f, 0.f, 0.f, 0.f};
#pragma unroll
    for (int kc = 0; kc < 4; ++kc) {
#pragma unroll
      for (int rt = 0; rt < 4; ++rt) {
        int row = rt * 16 + r16;
        int sw = (row & 7) << 2;
        int base = R0 + row * 132 + kc * 32;
        uint4 wa = *(const uint4*)&Li[base + ((g * 8) ^ sw)];
        uint4 wb = *(const uint4*)&Li[base + ((g * 8 + 4) ^ sw)];
        BU ah, al;
        ah.u[0] = __builtin_amdgcn_perm(wa.y, wa.x, SELH);
        ah.u[1] = __builtin_amdgcn_perm(wa.w, wa.z, SELH);
        ah.u[2] = __builtin_amdgcn_perm(wb.y, wb.x, SELH);
        ah.u[3] = __builtin_amdgcn_perm(wb.w, wb.z, SELH);
        al.u[0] = __builtin_amdgcn_perm(wa.y, wa.x, SELL);
        al.u[1] = __builtin_amdgcn_perm(wa.w, wa.z, SELL);
        al.u[2] = __builtin_amdgcn_perm(wb.y, wb.x, SELL);
        al.u[3] = __builtin_amdgcn_perm(wb.w, wb.z, SELL);
#pragma unroll
        for (int ci = 0; ci < 2; ++ci) {
          BU bh, bl;
          bh.q = wih[ci][kc];
          bl.q = wil[ci][kc];
          acc[rt][ci] = __builtin_amdgcn_mfma_f32_16x16x32_bf16(al.v, bh.v, acc[rt][ci], 0, 0, 0);
          acc[rt][ci] = __builtin_amdgcn_mfma_f32_16x16x32_bf16(ah.v, bl.v, acc[rt][ci], 0, 0, 0);
          acc[rt][ci] = __builtin_amdgcn_mfma_f32_16x16x32_bf16(ah.v, bh.v, acc[rt][ci], 0, 0, 0);
        }
      }
    }
    __syncthreads();   // all H reads done before R0 is overwritten

    // ---- P2: scatter: waves 0-3 -> x f32 [t][132] (R0); 4-7 -> silu(z) [d][68]
    {
      int dl0 = (w & 3) * 32;
      if (w < 4) {
#pragma unroll
        for (int rt = 0; rt < 4; ++rt)
#pragma unroll
          for (int ci = 0; ci < 2; ++ci)
#pragma unroll
            for (int r = 0; r < 4; ++r)
              L[R0 + (rt * 16 + g * 4 + r) * 132 + dl0 + ci * 16 + r16] = acc[rt][ci][r];
      } else {
#pragma unroll
        for (int rt = 0; rt < 4; ++rt)
#pragma unroll
          for (int ci = 0; ci < 2; ++ci)
#pragma unroll
            for (int r = 0; r < 4; ++r)
              L[R1 + (dl0 + ci * 16 + r16) * 68 + rt * 16 + g * 4 + r] = fsilu(acc[rt][ci][r]);
      }
    }
    __syncthreads();

    // ---- P3: causal conv(3) + SiLU; write packed XC (swizzled, R0) + f32 [d][t]
    {
      int t0 = tq * 16;
      float xin[18];
#pragma unroll
      for (int ii = 0; ii < 18; ++ii) {
        int t = t0 - 2 + ii;
        xin[ii] = (t < 0) ? 0.f : L[R0 + t * 132 + dc];
      }
      __syncthreads();   // all pre-conv reads done before overwrite
      float sv[16];
#pragma unroll
      for (int ii = 0; ii < 16; ++ii) {
        float v = fmaf(cw2, xin[ii + 2], fmaf(cw1, xin[ii + 1], fmaf(cw0, xin[ii], cbv)));
        sv[ii] = fsilu(v);
      }
#pragma unroll
      for (int ii = 0; ii < 16; ++ii) {
        int t = t0 + ii;
        Li[R0 + t * 132 + (dc ^ ((t & 7) << 2))] = packsplit(sv[ii]);
      }
#pragma unroll
      for (int qq = 0; qq < 4; ++qq)
        *(float4*)&L[RXT + dc * 68 + t0 + qq * 4] =
            make_float4(sv[qq * 4], sv[qq * 4 + 1], sv[qq * 4 + 2], sv[qq * 4 + 3]);
    }
    __syncthreads();

    // ---- P4: x_proj x_dbl(64x16) = XC @ Wx^T via MFMA (waves 0-3) ----
    if (w < 4) {
      f32x4 o = (f32x4){0.f, 0.f, 0.f, 0.f};
#pragma unroll
      for (int kc = 0; kc < 4; ++kc) {
        int cb = (r16 * 4 + kc) * 8 + g * 2;
        BU bh, bl;
        bh.q = wsx4[cb];
        bl.q = wsx4[cb + 1];
        int row = w * 16 + r16;
        int sw = (row & 7) << 2;
        int base = R0 + row * 132 + kc * 32;
        uint4 wa = *(const uint4*)&Li[base + ((g * 8) ^ sw)];
        uint4 wb = *(const uint4*)&Li[base + ((g * 8 + 4) ^ sw)];
        BU ah, al;
        ah.u[0] = __builtin_amdgcn_perm(wa.y, wa.x, SELH);
        ah.u[1] = __builtin_amdgcn_perm(wa.w, wa.z, SELH);
        ah.u[2] = __builtin_amdgcn_perm(wb.y, wb.x, SELH);
        ah.u[3] = __builtin_amdgcn_perm(wb.w, wb.z, SELH);
        al.u[0] = __builtin_amdgcn_perm(wa.y, wa.x, SELL);
        al.u[1] = __builtin_amdgcn_perm(wa.w, wa.z, SELL);
        al.u[2] = __builtin_amdgcn_perm(wb.y, wb.x, SELL);
        al.u[3] = __builtin_amdgcn_perm(wb.w, wb.z, SELL);
        o = __builtin_amdgcn_mfma_f32_16x16x32_bf16(al.v, bh.v, o, 0, 0, 0);
        o = __builtin_amdgcn_mfma_f32_16x16x32_bf16(ah.v, bl.v, o, 0, 0, 0);
        o = __builtin_amdgcn_mfma_f32_16x16x32_bf16(ah.v, bh.v, o, 0, 0, 0);
      }
      // scatter x_dbl row r16 into interleaved per-s slots
      int p = (r16 < 8) ? ((r16 >> 1) * 4 + (r16 & 1))
                        : (r16 < 12 ? (r16 - 8) * 4 + 2 : (r16 - 12) * 4 + 3);
#pragma unroll
      for (int q = 0; q < 4; ++q)
        L[RXD + (w * 16 + g * 4 + q) * 20 + p] = o[q];
    }
    __syncthreads();

    // ---- P5: selective scan, 128 d x 4 s; packed Y -> R0 (swizzled) ----
    {
      float h = 0.f;
#pragma unroll
      for (int tb = 0; tb < 16; ++tb) {
        float4 xq = *(const float4*)&L[RXT + ds * 68 + tb * 4];
        float4 zq = *(const float4*)&L[R1 + ds * 68 + tb * 4];
        float xcl[4] = {xq.x, xq.y, xq.z, xq.w};
        float zl[4] = {zq.x, zq.y, zq.z, zq.w};
#pragma unroll
        for (int si = 0; si < 4; ++si) {
          int t = tb * 4 + si;
          float4 xd = *(const float4*)&L[RXD + t * 20 + ss * 4];
          float dtv = qsum4(fmaf(xd.x, wA, xd.y * wB)) + bd;
          float e = __builtin_amdgcn_exp2f(dtv * LOG2E);
          float sp = LN2 * __builtin_amdgcn_logf(1.0f + e);
          dtv = (dtv > 20.f) ? dtv : sp;               // softplus
          float xcv = xcl[si];
          float dA = __builtin_amdgcn_exp2f(dtv * As2);
          h = fmaf(h, dA, dtv * xcv * xd.z);
          float y = qsum4(h * xd.w);                   // sum over 4 states
          if (si == ss) {
            y = fmaf(xcv, Dd, y);
            y *= zl[si];
            Li[R0 + t * 132 + (ds ^ ((t & 7) << 2))] = packsplit(y);
          }
        }
      }
    }
    __syncthreads();

    // ---- P6: out_proj out(64x128) = Y @ Wout^T ----
    {
      f32x4 o[4];
#pragma unroll
      for (int rt = 0; rt < 4; ++rt) o[rt] = (f32x4){0.f, 0.f, 0.f, 0.f};
#pragma unroll
      for (int kc = 0; kc < 4; ++kc) {
        BU bh, bl;
        bh.q = woh[kc];
        bl.q = wol[kc];
#pragma unroll
        for (int rt = 0; rt < 4; ++rt) {
          int row = rt * 16 + r16;
          int sw = (row & 7) << 2;
          int base = R0 + row * 132 + kc * 32;
          uint4 wa = *(const uint4*)&Li[base + ((g * 8) ^ sw)];
          uint4 wb = *(const uint4*)&Li[base + ((g * 8 + 4) ^ sw)];
          BU ah, al;
          ah.u[0] = __builtin_amdgcn_perm(wa.y, wa.x, SELH);
          ah.u[1] = __builtin_amdgcn_perm(wa.w, wa.z, SELH);
          ah.u[2] = __builtin_amdgcn_perm(wb.y, wb.x, SELH);
          ah.u[3] = __builtin_amdgcn_perm(wb.w, wb.z, SELH);
          al.u[0] = __builtin_amdgcn_perm(wa.y, wa.x, SELL);
          al.u[1] = __builtin_amdgcn_perm(wa.w, wa.z, SELL);
          al.u[2] = __builtin_amdgcn_perm(wb.y, wb.x, SELL);
          al.u[3] = __builtin_amdgcn_perm(wb.w, wb.z, SELL);
          o[rt] = __builtin_amdgcn_mfma_f32_16x16x32_bf16(al.v, bh.v, o[rt], 0, 0, 0);
          o[rt] = __builtin_amdgcn_mfma_f32_16x16x32_bf16(ah.v, bl.v, o[rt], 0, 0, 0);
          o[rt] = __builtin_amdgcn_mfma_f32_16x16x32_bf16(ah.v, bh.v, o[rt], 0, 0, 0);
        }
      }
#pragma unroll
      for (int rt = 0; rt < 4; ++rt)
#pragma unroll
        for (int r = 0; r < 4; ++r)
          hseq[(rt * 16 + g * 4 + r) * C_ + w * 16 + r16] = o[rt][r];
    }
    __syncthreads();   // R0/R1/RXT reuse next sequence
  }
}

// ---------------- K3: transpose (B*N,T,C) -> (B,C,T,N) ----------------------
__global__ __launch_bounds__(256) void k_out_tr(const float* __restrict__ ws_y,
                                                float* __restrict__ out) {
  __shared__ float tile[32 * 132];
  int bx = blockIdx.x;
  int nt = bx & 7, t = (bx >> 3) & 63, b = bx >> 9;
  int n0 = nt * 32;
  int tid = threadIdx.x;
  const float4* y4 = (const float4*)ws_y;
  for (int it = 0; it < 4; ++it) {
    int idx4 = it * 256 + tid;
    int nn = idx4 >> 5, c4 = idx4 & 31;
    float4 v = y4[((b * N_ + n0 + nn) * (long)T_ + t) * (C_ / 4) + c4];
    *(float4*)&tile[nn * 132 + c4 * 4] = v;
  }
  __syncthreads();
  int nn = tid & 31, cg = tid >> 5;
  for (int i = 0; i < 16; ++i) {
    int c = cg * 16 + i;
    out[((b * C_ + c) * (long)T_ + t) * N_ + n0 + nn] = tile[nn * 132 + c];
  }
}

extern "C" void kernel_launch(void* const* d_in, const int* in_sizes, int n_in,
                              void* d_out, int out_size, void* d_ws, size_t ws_size,
                              hipStream_t stream) {
  const float* x    = (const float*)d_in[0];
  const float* gam  = (const float*)d_in[1];
  const float* bet  = (const float*)d_in[2];
  const float* Win  = (const float*)d_in[3];
  const float* cw   = (const float*)d_in[4];
  const float* cb   = (const float*)d_in[5];
  const float* Wx   = (const float*)d_in[6];
  const float* Wdt  = (const float*)d_in[7];
  const float* bdt  = (const float*)d_in[8];
  const float* Alog = (const float*)d_in[9];
  const float* Dp   = (const float*)d_in[10];
  const float* Wout = (const float*)d_in[11];
  float* out = (float*)d_out;
  float* ws  = (float*)d_ws;   // 64 MiB: (B*N, T, C) fp32, in-place H -> y

  // split-weight storage: ws tail if it fits, else scribble d_out
  // (K3 fully overwrites d_out afterwards; stream order makes this safe)
  const size_t HBYTES = 67108864ull;                      // 64 MiB
  const size_t WBYTES = 131072ull + 65536ull + 8192ull;   // Win + Wout + Wx splits
  char* wtail;
  if (ws_size >= HBYTES + WBYTES) wtail = (char*)d_ws + HBYTES;
  else                            wtail = (char*)d_out;
  ushort_t* wsi = (ushort_t*)wtail;
  ushort_t* wso = (ushort_t*)(wtail + 131072);
  ushort_t* wsx = (ushort_t*)(wtail + 131072 + 65536);

  (void)hipFuncSetAttribute((const void*)k_mamba,
                            hipFuncAttributeMaxDynamicSharedMemorySize,
                            LDSW * 4);

  k_wsplit<<<4, 512, 0, stream>>>(Win, Wout, Wx, wsi, wso, wsx);
  k_ln<<<4096, 256, 0, stream>>>(x, gam, bet, ws);
  k_mamba<<<2048 / NSEQ, 512, LDSW * 4, stream>>>(ws, wsi, wso, wsx, cw, cb,
                                                  Wdt, bdt, Alog, Dp);
  k_out_tr<<<4096, 256, 0, stream>>>(ws, out);
}